// Round 7
// baseline (279.947 us; speedup 1.0000x reference)
//
#include <hip/hip_runtime.h>
#include <hip/hip_bf16.h>
#include <stdint.h>

#define N_VOX 131072
#define KVOL  27
#define PPK   65536
#define CIN   64
#define COUT  64
#define TOT   (KVOL * PPK)         // 1769472 pairs
#define SORT_BLOCKS 864            // hist/scatter blocks, 2048 pairs each
#define GEMM_BLOCKS (KVOL * (PPK / 128))  // 13824
#define NB    512                  // buckets = key>>8 (256 keys each)

typedef __attribute__((ext_vector_type(8))) short short8;
typedef __attribute__((ext_vector_type(4))) float f32x4;

// inclusive Hillis-Steele scan over 512 ints in s[] using 256 threads
#define SCAN512(s, tid)                                       \
  for (int off = 1; off < 512; off <<= 1) {                   \
    int va_ = ((tid) >= off) ? s[(tid) - off] : 0;            \
    int vb_ = (((tid) + 256) >= off) ? s[(tid) + 256 - off] : 0; \
    __syncthreads();                                          \
    s[(tid)] += va_; s[(tid) + 256] += vb_;                   \
    __syncthreads();                                          \
  }

__device__ __forceinline__ void gl_lds16(const void* g, void* l) {
  __builtin_amdgcn_global_load_lds(
      (const __attribute__((address_space(1))) unsigned int*)g,
      (__attribute__((address_space(3))) unsigned int*)l,
      16, 0, 0);
}

__device__ __forceinline__ unsigned short f2bf(float f) {
  __hip_bfloat16 h = __float2bfloat16(f);
  return *reinterpret_cast<unsigned short*>(&h);
}

// ---------------- k1: fused cast + weight transpose + bucket histogram ----------------
// blocks [0,864): LDS-hist 2048 keys into 512 hi-buckets, coalesced counts store
// (layout [block][bucket], NO global atomics). then 4096 cast + 27 wt blocks.

__global__ __launch_bounds__(256) void prep_hist_kernel(
    const float* __restrict__ in, unsigned short* __restrict__ inb,
    const float* __restrict__ w, unsigned short* __restrict__ wt,
    const int* __restrict__ omap, int* __restrict__ counts, int do_sort) {
  int b = blockIdx.x;
  if (do_sort) {
    if (b < SORT_BLOCKS) {
      __shared__ unsigned int hist[NB];
      int tid = threadIdx.x;
      hist[tid] = 0; hist[tid + 256] = 0;
      __syncthreads();
      int e0 = (b * 256 + tid) * 8;
      int4 o0 = *(const int4*)(omap + e0);
      int4 o1 = *(const int4*)(omap + e0 + 4);
      atomicAdd(&hist[(unsigned)o0.x >> 8], 1u);
      atomicAdd(&hist[(unsigned)o0.y >> 8], 1u);
      atomicAdd(&hist[(unsigned)o0.z >> 8], 1u);
      atomicAdd(&hist[(unsigned)o0.w >> 8], 1u);
      atomicAdd(&hist[(unsigned)o1.x >> 8], 1u);
      atomicAdd(&hist[(unsigned)o1.y >> 8], 1u);
      atomicAdd(&hist[(unsigned)o1.z >> 8], 1u);
      atomicAdd(&hist[(unsigned)o1.w >> 8], 1u);
      __syncthreads();
      counts[(size_t)b * NB + tid]       = (int)hist[tid];
      counts[(size_t)b * NB + tid + 256] = (int)hist[tid + 256];
      return;
    }
    b -= SORT_BLOCKS;
  }
  if (b < 4096) {
    int i = b * 256 + threadIdx.x;
    const float4* in4 = (const float4*)in;
    float4 f0 = in4[2 * i], f1 = in4[2 * i + 1];
    union { unsigned short u[8]; short8 v; } r;
    r.u[0] = f2bf(f0.x); r.u[1] = f2bf(f0.y); r.u[2] = f2bf(f0.z); r.u[3] = f2bf(f0.w);
    r.u[4] = f2bf(f1.x); r.u[5] = f2bf(f1.y); r.u[6] = f2bf(f1.z); r.u[7] = f2bf(f1.w);
    ((short8*)inb)[i] = r.v;
  } else {
    int k = b - 4096;
    const float* wk = w + k * CIN * COUT;
    unsigned short* wtk = wt + k * CIN * COUT;
    for (int idx = threadIdx.x; idx < CIN * COUT; idx += 256) {
      int c = idx >> 6, o = idx & 63;
      wtk[o * 64 + c] = f2bf(wk[idx]);
    }
  }
}

// ---------------- k2: per-bucket exclusive scan over the 864 block counts ----------------

__global__ __launch_bounds__(256) void scan_blocks_kernel(
    const int* __restrict__ counts, int* __restrict__ blockbase,
    int* __restrict__ totals) {
  __shared__ int s[256];
  int b = blockIdx.x, t = threadIdx.x;
  int c0 = 0, c1 = 0, c2 = 0, c3 = 0;
  if (t < 216) {
    c0 = counts[(size_t)(4 * t + 0) * NB + b];
    c1 = counts[(size_t)(4 * t + 1) * NB + b];
    c2 = counts[(size_t)(4 * t + 2) * NB + b];
    c3 = counts[(size_t)(4 * t + 3) * NB + b];
  }
  int sum = c0 + c1 + c2 + c3;
  s[t] = sum; __syncthreads();
  for (int off = 1; off < 256; off <<= 1) {
    int v = (t >= off) ? s[t - off] : 0;
    __syncthreads();
    s[t] += v;
    __syncthreads();
  }
  int excl = s[t] - sum;
  int* brow = blockbase + (size_t)b * SORT_BLOCKS;
  if (t < 216) {
    brow[t * 4]     = excl;
    brow[t * 4 + 1] = excl + c0;
    brow[t * 4 + 2] = excl + c0 + c1;
    brow[t * 4 + 3] = excl + c0 + c1 + c2;
  }
  if (t == 255) totals[b] = s[255];
}

// ---------------- k3: scatter packed pairs into bucket regions ----------------
// redundant LDS scan of totals -> bbase (kills base_kernel); pairs[pos]=(e<<8)|lo.

__global__ __launch_bounds__(256) void scatter_kernel(
    const int* __restrict__ omap, const int* __restrict__ blockbase,
    const int* __restrict__ totals, unsigned int* __restrict__ pairs) {
  __shared__ int ts[NB];
  __shared__ unsigned int gb[NB];
  __shared__ unsigned int cur[NB];
  int b = blockIdx.x, tid = threadIdx.x;
  int t0 = totals[tid], t1 = totals[tid + 256];
  ts[tid] = t0; ts[tid + 256] = t1;
  __syncthreads();
  SCAN512(ts, tid);
  gb[tid]       = (unsigned)(ts[tid] - t0 +
                    blockbase[(size_t)tid * SORT_BLOCKS + b]);
  gb[tid + 256] = (unsigned)(ts[tid + 256] - t1 +
                    blockbase[(size_t)(tid + 256) * SORT_BLOCKS + b]);
  cur[tid] = 0; cur[tid + 256] = 0;
  __syncthreads();
  int e0 = (b * 256 + tid) * 8;
  int4 o0 = *(const int4*)(omap + e0);
  int4 o1 = *(const int4*)(omap + e0 + 4);
  unsigned int key[8] = {(unsigned)o0.x, (unsigned)o0.y, (unsigned)o0.z, (unsigned)o0.w,
                         (unsigned)o1.x, (unsigned)o1.y, (unsigned)o1.z, (unsigned)o1.w};
#pragma unroll
  for (int i = 0; i < 8; i++) {
    unsigned int bk = key[i] >> 8;
    unsigned int r = atomicAdd(&cur[bk], 1u);
    unsigned int pos = gb[bk] + r;
    pairs[pos] = (((unsigned)(e0 + i)) << 8) | (key[i] & 255u);
  }
}

// ---------------- k4: refine buckets to full-key order ----------------
// one block per bucket: coalesced pairs read, LDS-hist 256 lo-bins, LDS scan ->
// exact ofs/cnt for all rows; islotf[e] = final slot (scattered 4B write).
// Store then needs ONE coalesced read -- no gather (r6's fmap FETCH bloat).

__global__ __launch_bounds__(256) void refine_kernel(
    const unsigned int* __restrict__ pairs, const int* __restrict__ totals,
    int* __restrict__ islotf, int* __restrict__ ofs, int* __restrict__ cnt) {
  __shared__ int ts[NB];
  __shared__ unsigned int hist[256];
  __shared__ unsigned int scn[256];
  __shared__ unsigned int cur[256];
  int b = blockIdx.x, t = threadIdx.x;
  int t0 = totals[t], t1 = totals[t + 256];
  ts[t] = t0; ts[t + 256] = t1;
  hist[t] = 0;
  __syncthreads();
  SCAN512(ts, t);
  __shared__ int sb_s, n_s;
  if (t == 0) { n_s = totals[b]; sb_s = ts[b] - n_s; }
  __syncthreads();
  int sb = sb_s, n = n_s;

  for (int i = t; i < n; i += 256)
    atomicAdd(&hist[pairs[sb + i] & 255u], 1u);
  __syncthreads();
  unsigned int h = hist[t];
  scn[t] = h;
  __syncthreads();
  for (int off = 1; off < 256; off <<= 1) {
    unsigned int v = (t >= off) ? scn[t - off] : 0;
    __syncthreads();
    scn[t] += v;
    __syncthreads();
  }
  unsigned int excl = scn[t] - h;
  ofs[b * 256 + t] = sb + (int)excl;
  cnt[b * 256 + t] = (int)h;
  cur[t] = excl;
  __syncthreads();
  for (int i = t; i < n; i += 256) {
    unsigned int v = pairs[sb + i];
    unsigned int r = atomicAdd(&cur[v & 255u], 1u);
    islotf[v >> 8] = sb + (int)r;
  }
}

// ---------------- k5: gather -> MFMA -> nt-store rows at fully-sorted positions ----------------

__global__ __launch_bounds__(256) void spconv_store_kernel(
    const unsigned short* __restrict__ inb,   // [N][64] bf16
    const unsigned short* __restrict__ wt,    // [27][COUT][CIN] bf16
    const int* __restrict__ imap,
    const int* __restrict__ islotf,           // e -> final slot (direct)
    unsigned short* __restrict__ contrib) {   // [TOT][64] bf16, key-sorted
  __shared__ __align__(16) char smem[24576];
  short* A_lds = (short*)smem;            // 16 KB: 128 pairs x 64 cin (fragment-major)
  short* B_lds = (short*)(smem + 16384);  //  8 KB: 64 cout x 64 cin
  short* C_sh  = (short*)smem;            // epilogue: [128][72] bf16
  __shared__ int perm_s[128];

  int bid = blockIdx.x;
  int k = bid >> 9;
  int pbase = (bid & 511) * 128;
  int tid = threadIdx.x;
  int wave = tid >> 6, lane = tid & 63;
  int m = lane & 15, q = lane >> 4;

  const int* imk = imap + k * PPK;
  const unsigned short* wtk = wt + k * 4096;

  if (tid < 128) perm_s[tid] = islotf[k * PPK + pbase + tid];

#pragma unroll
  for (int i = 0; i < 2; i++) {
    int id = wave * 2 + i;
    int t = id >> 1, s = id & 1;
    const unsigned short* g = wtk + (t * 16 + m) * 64 + s * 32 + q * 8;
    gl_lds16(g, &B_lds[(t * 128 + s * 64) * 8]);
  }
#pragma unroll
  for (int j = 0; j < 2; j++) {
    int r = wave * 2 + j;
    int row = imk[pbase + r * 16 + m];
    const unsigned short* g0 = inb + row * 64 + q * 8;
    gl_lds16(g0,      &A_lds[(r * 128)      * 8]);
    gl_lds16(g0 + 32, &A_lds[(r * 128 + 64) * 8]);
  }
  __syncthreads();

  const short8* Af = (const short8*)A_lds;
  const short8* Bf = (const short8*)B_lds;

  short8 a[2][2], b[4][2];
#pragma unroll
  for (int r2 = 0; r2 < 2; r2++) {
    int r = wave * 2 + r2;
#pragma unroll
    for (int s = 0; s < 2; s++) a[r2][s] = Af[r * 128 + s * 64 + lane];
  }
#pragma unroll
  for (int t = 0; t < 4; t++)
#pragma unroll
    for (int s = 0; s < 2; s++) b[t][s] = Bf[t * 128 + s * 64 + lane];

  __syncthreads();   // frag reads done before LDS reuse for C

  f32x4 acc[2][4];
#pragma unroll
  for (int r2 = 0; r2 < 2; r2++)
#pragma unroll
    for (int t = 0; t < 4; t++) {
      f32x4 c = {0.f, 0.f, 0.f, 0.f};
      c = __builtin_amdgcn_mfma_f32_16x16x32_bf16(a[r2][0], b[t][0], c, 0, 0, 0);
      c = __builtin_amdgcn_mfma_f32_16x16x32_bf16(a[r2][1], b[t][1], c, 0, 0, 0);
      acc[r2][t] = c;
    }

  // C layout: row(pair) = q*4 + reg, col(cout) = t*16 + m
#pragma unroll
  for (int r2 = 0; r2 < 2; r2++) {
    int pl = (wave * 2 + r2) * 16 + q * 4;
#pragma unroll
    for (int t = 0; t < 4; t++)
#pragma unroll
      for (int reg = 0; reg < 4; reg++)
        C_sh[(pl + reg) * 72 + t * 16 + m] = (short)f2bf(acc[r2][t][reg]);
  }
  __syncthreads();

  // nontemporal full-line stores to fully-sorted slots
#pragma unroll
  for (int i = 0; i < 4; i++) {
    int id = i * 256 + tid;
    int row = id >> 3, ch = (id & 7) * 8;
    short8 v = *(const short8*)&C_sh[row * 72 + ch];
    __builtin_nontemporal_store(v, (short8*)&contrib[(size_t)perm_s[row] * 64 + ch]);
  }
}

// ---------------- k6: contiguous segmented reduce + bias ----------------
// CACHED loads: r4 counters proved L3 serves ~50% of contrib even with nt;
// plain loads harvest Infinity-Cache residency of the freshly-written contrib.

__global__ __launch_bounds__(256) void reduce_kernel(
    const unsigned short* __restrict__ contrib,
    const int* __restrict__ ofs,
    const int* __restrict__ cnt,
    const float* __restrict__ bias,
    float* __restrict__ out) {
  int row = blockIdx.x * 4 + (threadIdx.x >> 6);
  int lane = threadIdx.x & 63;
  int rg = lane >> 3, ch = (lane & 7) * 8;
  int s = ofs[row], n = cnt[row];

  float acc[8];
#pragma unroll
  for (int i = 0; i < 8; i++) acc[i] = 0.f;

  int j = rg;
  for (; j + 8 < n; j += 16) {
    short8 v0 = *((const short8*)&contrib[(size_t)(s + j) * 64 + ch]);
    short8 v1 = *((const short8*)&contrib[(size_t)(s + j + 8) * 64 + ch]);
#pragma unroll
    for (int i = 0; i < 8; i++)
      acc[i] += __uint_as_float((unsigned int)(unsigned short)v0[i] << 16);
#pragma unroll
    for (int i = 0; i < 8; i++)
      acc[i] += __uint_as_float((unsigned int)(unsigned short)v1[i] << 16);
  }
  if (j < n) {
    short8 v0 = *((const short8*)&contrib[(size_t)(s + j) * 64 + ch]);
#pragma unroll
    for (int i = 0; i < 8; i++)
      acc[i] += __uint_as_float((unsigned int)(unsigned short)v0[i] << 16);
  }

#pragma unroll
  for (int mask = 8; mask < 64; mask <<= 1)
#pragma unroll
    for (int i = 0; i < 8; i++) acc[i] += __shfl_xor(acc[i], mask, 64);

  if (rg == 0) {
    float4 b0 = *(const float4*)(bias + ch);
    float4 b1 = *(const float4*)(bias + ch + 4);
    float4 r0 = {acc[0] + b0.x, acc[1] + b0.y, acc[2] + b0.z, acc[3] + b0.w};
    float4 r1 = {acc[4] + b1.x, acc[5] + b1.y, acc[6] + b1.z, acc[7] + b1.w};
    *(float4*)(out + (size_t)row * 64 + ch) = r0;
    *(float4*)(out + (size_t)row * 64 + ch + 4) = r1;
  }
}

// ---------------- fallback (atomic path) ----------------

__global__ __launch_bounds__(256) void init_out_kernel(float* __restrict__ out,
                                                       const float* __restrict__ bias) {
  int i = blockIdx.x * blockDim.x + threadIdx.x;
  float4 b = *(const float4*)(bias + ((i * 4) & 63));
  ((float4*)out)[i] = b;
}

__global__ __launch_bounds__(256) void spconv_atomic_kernel(
    const unsigned short* __restrict__ inb,
    const unsigned short* __restrict__ wt,
    const int* __restrict__ imap, const int* __restrict__ omap,
    float* __restrict__ out) {
  __shared__ __align__(16) short A_lds[128 * 64];
  __shared__ __align__(16) short B_lds[64 * 64];

  int bid = blockIdx.x;
  int k = bid >> 9;
  int pbase = (bid & 511) * 128;
  int tid = threadIdx.x;
  int wave = tid >> 6, lane = tid & 63;
  int m = lane & 15, q = lane >> 4;

  const int* imk = imap + k * PPK;
  const int* omk = omap + k * PPK;
  const unsigned short* wtk = wt + k * 4096;

#pragma unroll
  for (int i = 0; i < 2; i++) {
    int id = wave * 2 + i;
    int t = id >> 1, s = id & 1;
    const unsigned short* g = wtk + (t * 16 + m) * 64 + s * 32 + q * 8;
    gl_lds16(g, &B_lds[(t * 128 + s * 64) * 8]);
  }
#pragma unroll
  for (int j = 0; j < 2; j++) {
    int r = wave * 2 + j;
    int row = imk[pbase + r * 16 + m];
    const unsigned short* g0 = inb + row * 64 + q * 8;
    gl_lds16(g0,      &A_lds[(r * 128)      * 8]);
    gl_lds16(g0 + 32, &A_lds[(r * 128 + 64) * 8]);
  }
  __syncthreads();

  const short8* Af = (const short8*)A_lds;
  const short8* Bf = (const short8*)B_lds;
  short8 a[2][2], b[4][2];
#pragma unroll
  for (int r2 = 0; r2 < 2; r2++) {
    int r = wave * 2 + r2;
#pragma unroll
    for (int s = 0; s < 2; s++) a[r2][s] = Af[r * 128 + s * 64 + lane];
  }
#pragma unroll
  for (int t = 0; t < 4; t++)
#pragma unroll
    for (int s = 0; s < 2; s++) b[t][s] = Bf[t * 128 + s * 64 + lane];

  f32x4 acc[2][4];
#pragma unroll
  for (int r2 = 0; r2 < 2; r2++)
#pragma unroll
    for (int t = 0; t < 4; t++) {
      f32x4 c = {0.f, 0.f, 0.f, 0.f};
      c = __builtin_amdgcn_mfma_f32_16x16x32_bf16(a[r2][0], b[t][0], c, 0, 0, 0);
      c = __builtin_amdgcn_mfma_f32_16x16x32_bf16(a[r2][1], b[t][1], c, 0, 0, 0);
      acc[r2][t] = c;
    }

  int orow[2][4];
#pragma unroll
  for (int r2 = 0; r2 < 2; r2++) {
    int pr = pbase + (wave * 2 + r2) * 16 + q * 4;
#pragma unroll
    for (int reg = 0; reg < 4; reg++) orow[r2][reg] = omk[pr + reg];
  }
#pragma unroll
  for (int r2 = 0; r2 < 2; r2++)
#pragma unroll
    for (int t = 0; t < 4; t++)
#pragma unroll
      for (int reg = 0; reg < 4; reg++)
        atomicAdd(out + (size_t)orow[r2][reg] * 64 + t * 16 + m, acc[r2][t][reg]);
}

// ---------------- launch ----------------

extern "C" void kernel_launch(void* const* d_in, const int* in_sizes, int n_in,
                              void* d_out, int out_size, void* d_ws, size_t ws_size,
                              hipStream_t stream) {
  const float* in_feats = (const float*)d_in[0];
  const float* kern     = (const float*)d_in[1];
  const float* bias     = (const float*)d_in[2];
  const int*   imap     = (const int*)d_in[3];
  const int*   omap     = (const int*)d_in[4];
  float* out = (float*)d_out;

  char* ws = (char*)d_ws;
  size_t off = 0;
  auto alloc = [&](size_t bytes) { size_t o = off; off = (off + bytes + 255) & ~(size_t)255; return o; };

  size_t o_inb   = alloc((size_t)N_VOX * CIN * 2);        // 16.78 MB
  size_t o_wt    = alloc((size_t)KVOL * CIN * COUT * 2);  // 0.22 MB
  size_t o_cts   = alloc((size_t)NB * SORT_BLOCKS * 4);   // 1.77 MB (ofs/cnt alias here)
  size_t o_bb    = alloc((size_t)NB * SORT_BLOCKS * 4);   // 1.77 MB
  size_t o_tot   = alloc((size_t)NB * 4);                 // 2 KB
  size_t o_islot = alloc((size_t)TOT * 4);                // 7.08 MB
  size_t o_ctb   = alloc((size_t)TOT * 64 * 2);           // 226.5 MB
  size_t needed = off;

  unsigned short* inb = (unsigned short*)(ws + o_inb);
  unsigned short* wt  = (unsigned short*)(ws + o_wt);
  int* counts    = (int*)(ws + o_cts);
  int* blockbase = (int*)(ws + o_bb);
  int* totals    = (int*)(ws + o_tot);
  int* islotf    = (int*)(ws + o_islot);
  unsigned short* ctb = (unsigned short*)(ws + o_ctb);
  // pairs (7.08 MB) aliases the ctb region: pairs lifetime [scatter, refine],
  // ctb lifetime [store, reduce] -- disjoint, stream-ordered.
  unsigned int* pairs = (unsigned int*)(ws + o_ctb);
  // ofs/cnt (1.05 MB) alias counts: counts dies after scan_blocks; refine writes
  // ofs/cnt strictly later -- disjoint, stream-ordered.
  int* ofs = (int*)(ws + o_cts);
  int* cnt = ofs + N_VOX;

  bool fast = (ws_size >= needed);

  if (fast) {
    prep_hist_kernel<<<SORT_BLOCKS + 4096 + KVOL, 256, 0, stream>>>(
        in_feats, inb, kern, wt, omap, counts, 1);
    scan_blocks_kernel<<<NB, 256, 0, stream>>>(counts, blockbase, totals);
    scatter_kernel<<<SORT_BLOCKS, 256, 0, stream>>>(omap, blockbase, totals, pairs);
    refine_kernel<<<NB, 256, 0, stream>>>(pairs, totals, islotf, ofs, cnt);
    spconv_store_kernel<<<GEMM_BLOCKS, 256, 0, stream>>>(inb, wt, imap, islotf, ctb);
    reduce_kernel<<<N_VOX / 4, 256, 0, stream>>>(ctb, ofs, cnt, bias, out);
  } else {
    prep_hist_kernel<<<4096 + KVOL, 256, 0, stream>>>(
        in_feats, inb, kern, wt, omap, nullptr, 0);
    init_out_kernel<<<(N_VOX * COUT / 4) / 256, 256, 0, stream>>>(out, bias);
    spconv_atomic_kernel<<<GEMM_BLOCKS, 256, 0, stream>>>(inb, wt, imap, omap, out);
  }
}

// Round 8
// 261.231 us; speedup vs baseline: 1.0716x; 1.0716x over previous
//
#include <hip/hip_runtime.h>
#include <hip/hip_bf16.h>
#include <stdint.h>

#define N_VOX 131072
#define KVOL  27
#define PPK   65536
#define CIN   64
#define COUT  64
#define TOT   (KVOL * PPK)         // 1769472 pairs
#define SORT_BLOCKS 864            // hist/scatter blocks, 2048 pairs each
#define GEMM_BLOCKS (KVOL * (PPK / 128))  // 13824
#define NB    512                  // buckets = key>>8 (256 keys each)

typedef __attribute__((ext_vector_type(8))) short short8;
typedef __attribute__((ext_vector_type(4))) float f32x4;

// inclusive Hillis-Steele scan over 512 ints in s[] using 256 threads
#define SCAN512(s, tid)                                       \
  for (int off = 1; off < 512; off <<= 1) {                   \
    int va_ = ((tid) >= off) ? s[(tid) - off] : 0;            \
    int vb_ = (((tid) + 256) >= off) ? s[(tid) + 256 - off] : 0; \
    __syncthreads();                                          \
    s[(tid)] += va_; s[(tid) + 256] += vb_;                   \
    __syncthreads();                                          \
  }

__device__ __forceinline__ void gl_lds16(const void* g, void* l) {
  __builtin_amdgcn_global_load_lds(
      (const __attribute__((address_space(1))) unsigned int*)g,
      (__attribute__((address_space(3))) unsigned int*)l,
      16, 0, 0);
}

__device__ __forceinline__ unsigned short f2bf(float f) {
  __hip_bfloat16 h = __float2bfloat16(f);
  return *reinterpret_cast<unsigned short*>(&h);
}

// ---------------- k1: fused cast + weight transpose + bucket histogram ----------------

__global__ __launch_bounds__(256) void prep_hist_kernel(
    const float* __restrict__ in, unsigned short* __restrict__ inb,
    const float* __restrict__ w, unsigned short* __restrict__ wt,
    const int* __restrict__ omap, int* __restrict__ counts, int do_sort) {
  int b = blockIdx.x;
  if (do_sort) {
    if (b < SORT_BLOCKS) {
      __shared__ unsigned int hist[NB];
      int tid = threadIdx.x;
      hist[tid] = 0; hist[tid + 256] = 0;
      __syncthreads();
      int e0 = (b * 256 + tid) * 8;
      int4 o0 = *(const int4*)(omap + e0);
      int4 o1 = *(const int4*)(omap + e0 + 4);
      atomicAdd(&hist[(unsigned)o0.x >> 8], 1u);
      atomicAdd(&hist[(unsigned)o0.y >> 8], 1u);
      atomicAdd(&hist[(unsigned)o0.z >> 8], 1u);
      atomicAdd(&hist[(unsigned)o0.w >> 8], 1u);
      atomicAdd(&hist[(unsigned)o1.x >> 8], 1u);
      atomicAdd(&hist[(unsigned)o1.y >> 8], 1u);
      atomicAdd(&hist[(unsigned)o1.z >> 8], 1u);
      atomicAdd(&hist[(unsigned)o1.w >> 8], 1u);
      __syncthreads();
      counts[(size_t)b * NB + tid]       = (int)hist[tid];
      counts[(size_t)b * NB + tid + 256] = (int)hist[tid + 256];
      return;
    }
    b -= SORT_BLOCKS;
  }
  if (b < 4096) {
    int i = b * 256 + threadIdx.x;
    const float4* in4 = (const float4*)in;
    float4 f0 = in4[2 * i], f1 = in4[2 * i + 1];
    union { unsigned short u[8]; short8 v; } r;
    r.u[0] = f2bf(f0.x); r.u[1] = f2bf(f0.y); r.u[2] = f2bf(f0.z); r.u[3] = f2bf(f0.w);
    r.u[4] = f2bf(f1.x); r.u[5] = f2bf(f1.y); r.u[6] = f2bf(f1.z); r.u[7] = f2bf(f1.w);
    ((short8*)inb)[i] = r.v;
  } else {
    int k = b - 4096;
    const float* wk = w + k * CIN * COUT;
    unsigned short* wtk = wt + k * CIN * COUT;
    for (int idx = threadIdx.x; idx < CIN * COUT; idx += 256) {
      int c = idx >> 6, o = idx & 63;
      wtk[o * 64 + c] = f2bf(wk[idx]);
    }
  }
}

// ---------------- k2: per-bucket exclusive scan over the 864 block counts ----------------

__global__ __launch_bounds__(256) void scan_blocks_kernel(
    const int* __restrict__ counts, int* __restrict__ blockbase,
    int* __restrict__ totals) {
  __shared__ int s[256];
  int b = blockIdx.x, t = threadIdx.x;
  int c0 = 0, c1 = 0, c2 = 0, c3 = 0;
  if (t < 216) {
    c0 = counts[(size_t)(4 * t + 0) * NB + b];
    c1 = counts[(size_t)(4 * t + 1) * NB + b];
    c2 = counts[(size_t)(4 * t + 2) * NB + b];
    c3 = counts[(size_t)(4 * t + 3) * NB + b];
  }
  int sum = c0 + c1 + c2 + c3;
  s[t] = sum; __syncthreads();
  for (int off = 1; off < 256; off <<= 1) {
    int v = (t >= off) ? s[t - off] : 0;
    __syncthreads();
    s[t] += v;
    __syncthreads();
  }
  int excl = s[t] - sum;
  int* brow = blockbase + (size_t)b * SORT_BLOCKS;
  if (t < 216) {
    brow[t * 4]     = excl;
    brow[t * 4 + 1] = excl + c0;
    brow[t * 4 + 2] = excl + c0 + c1;
    brow[t * 4 + 3] = excl + c0 + c1 + c2;
  }
  if (t == 255) totals[b] = s[255];
}

// ---------------- k3: scatter packed pairs into bucket regions ----------------

__global__ __launch_bounds__(256) void scatter_kernel(
    const int* __restrict__ omap, const int* __restrict__ blockbase,
    const int* __restrict__ totals, unsigned int* __restrict__ pairs) {
  __shared__ int ts[NB];
  __shared__ unsigned int gb[NB];
  __shared__ unsigned int cur[NB];
  int b = blockIdx.x, tid = threadIdx.x;
  int t0 = totals[tid], t1 = totals[tid + 256];
  ts[tid] = t0; ts[tid + 256] = t1;
  __syncthreads();
  SCAN512(ts, tid);
  gb[tid]       = (unsigned)(ts[tid] - t0 +
                    blockbase[(size_t)tid * SORT_BLOCKS + b]);
  gb[tid + 256] = (unsigned)(ts[tid + 256] - t1 +
                    blockbase[(size_t)(tid + 256) * SORT_BLOCKS + b]);
  cur[tid] = 0; cur[tid + 256] = 0;
  __syncthreads();
  int e0 = (b * 256 + tid) * 8;
  int4 o0 = *(const int4*)(omap + e0);
  int4 o1 = *(const int4*)(omap + e0 + 4);
  unsigned int key[8] = {(unsigned)o0.x, (unsigned)o0.y, (unsigned)o0.z, (unsigned)o0.w,
                         (unsigned)o1.x, (unsigned)o1.y, (unsigned)o1.z, (unsigned)o1.w};
#pragma unroll
  for (int i = 0; i < 8; i++) {
    unsigned int bk = key[i] >> 8;
    unsigned int r = atomicAdd(&cur[bk], 1u);
    unsigned int pos = gb[bk] + r;
    pairs[pos] = (((unsigned)(e0 + i)) << 8) | (key[i] & 255u);
  }
}

// ---------------- k4: refine buckets to full-key order ----------------

__global__ __launch_bounds__(256) void refine_kernel(
    const unsigned int* __restrict__ pairs, const int* __restrict__ totals,
    int* __restrict__ islotf, int* __restrict__ ofs, int* __restrict__ cnt) {
  __shared__ int ts[NB];
  __shared__ unsigned int hist[256];
  __shared__ unsigned int scn[256];
  __shared__ unsigned int cur[256];
  int b = blockIdx.x, t = threadIdx.x;
  int t0 = totals[t], t1 = totals[t + 256];
  ts[t] = t0; ts[t + 256] = t1;
  hist[t] = 0;
  __syncthreads();
  SCAN512(ts, t);
  __shared__ int sb_s, n_s;
  if (t == 0) { n_s = totals[b]; sb_s = ts[b] - n_s; }
  __syncthreads();
  int sb = sb_s, n = n_s;

  for (int i = t; i < n; i += 256)
    atomicAdd(&hist[pairs[sb + i] & 255u], 1u);
  __syncthreads();
  unsigned int h = hist[t];
  scn[t] = h;
  __syncthreads();
  for (int off = 1; off < 256; off <<= 1) {
    unsigned int v = (t >= off) ? scn[t - off] : 0;
    __syncthreads();
    scn[t] += v;
    __syncthreads();
  }
  unsigned int excl = scn[t] - h;
  ofs[b * 256 + t] = sb + (int)excl;
  cnt[b * 256 + t] = (int)h;
  cur[t] = excl;
  __syncthreads();
  for (int i = t; i < n; i += 256) {
    unsigned int v = pairs[sb + i];
    unsigned int r = atomicAdd(&cur[v & 255u], 1u);
    islotf[v >> 8] = sb + (int)r;
  }
}

// ---------------- k5: gather -> MFMA -> nt-store rows at fully-sorted positions ----------------

__global__ __launch_bounds__(256) void spconv_store_kernel(
    const unsigned short* __restrict__ inb,   // [N][64] bf16
    const unsigned short* __restrict__ wt,    // [27][COUT][CIN] bf16
    const int* __restrict__ imap,
    const int* __restrict__ islotf,           // e -> final slot (direct)
    unsigned short* __restrict__ contrib) {   // [TOT][64] bf16, key-sorted
  __shared__ __align__(16) char smem[24576];
  short* A_lds = (short*)smem;            // 16 KB: 128 pairs x 64 cin (fragment-major)
  short* B_lds = (short*)(smem + 16384);  //  8 KB: 64 cout x 64 cin
  short* C_sh  = (short*)smem;            // epilogue: [128][72] bf16
  __shared__ int perm_s[128];

  int bid = blockIdx.x;
  int k = bid >> 9;
  int pbase = (bid & 511) * 128;
  int tid = threadIdx.x;
  int wave = tid >> 6, lane = tid & 63;
  int m = lane & 15, q = lane >> 4;

  const int* imk = imap + k * PPK;
  const unsigned short* wtk = wt + k * 4096;

  if (tid < 128) perm_s[tid] = islotf[k * PPK + pbase + tid];

#pragma unroll
  for (int i = 0; i < 2; i++) {
    int id = wave * 2 + i;
    int t = id >> 1, s = id & 1;
    const unsigned short* g = wtk + (t * 16 + m) * 64 + s * 32 + q * 8;
    gl_lds16(g, &B_lds[(t * 128 + s * 64) * 8]);
  }
#pragma unroll
  for (int j = 0; j < 2; j++) {
    int r = wave * 2 + j;
    int row = imk[pbase + r * 16 + m];
    const unsigned short* g0 = inb + row * 64 + q * 8;
    gl_lds16(g0,      &A_lds[(r * 128)      * 8]);
    gl_lds16(g0 + 32, &A_lds[(r * 128 + 64) * 8]);
  }
  __syncthreads();

  const short8* Af = (const short8*)A_lds;
  const short8* Bf = (const short8*)B_lds;

  short8 a[2][2], b[4][2];
#pragma unroll
  for (int r2 = 0; r2 < 2; r2++) {
    int r = wave * 2 + r2;
#pragma unroll
    for (int s = 0; s < 2; s++) a[r2][s] = Af[r * 128 + s * 64 + lane];
  }
#pragma unroll
  for (int t = 0; t < 4; t++)
#pragma unroll
    for (int s = 0; s < 2; s++) b[t][s] = Bf[t * 128 + s * 64 + lane];

  __syncthreads();   // frag reads done before LDS reuse for C

  f32x4 acc[2][4];
#pragma unroll
  for (int r2 = 0; r2 < 2; r2++)
#pragma unroll
    for (int t = 0; t < 4; t++) {
      f32x4 c = {0.f, 0.f, 0.f, 0.f};
      c = __builtin_amdgcn_mfma_f32_16x16x32_bf16(a[r2][0], b[t][0], c, 0, 0, 0);
      c = __builtin_amdgcn_mfma_f32_16x16x32_bf16(a[r2][1], b[t][1], c, 0, 0, 0);
      acc[r2][t] = c;
    }

  // C layout: row(pair) = q*4 + reg, col(cout) = t*16 + m
#pragma unroll
  for (int r2 = 0; r2 < 2; r2++) {
    int pl = (wave * 2 + r2) * 16 + q * 4;
#pragma unroll
    for (int t = 0; t < 4; t++)
#pragma unroll
      for (int reg = 0; reg < 4; reg++)
        C_sh[(pl + reg) * 72 + t * 16 + m] = (short)f2bf(acc[r2][t][reg]);
  }
  __syncthreads();

  // nontemporal full-line stores to fully-sorted slots
#pragma unroll
  for (int i = 0; i < 4; i++) {
    int id = i * 256 + tid;
    int row = id >> 3, ch = (id & 7) * 8;
    short8 v = *(const short8*)&C_sh[row * 72 + ch];
    __builtin_nontemporal_store(v, (short8*)&contrib[(size_t)perm_s[row] * 64 + ch]);
  }
}

// ---------------- k6: contiguous segmented reduce + bias (r6-proven nt loads) ----------------
// nt loads: contrib is a 226.5 MB read-once stream >> L2; allocate-on-read
// (r7's cached loads) cost ~16 us. nt still probes L3 (r4: ~50% served).

__global__ __launch_bounds__(256) void reduce_kernel(
    const unsigned short* __restrict__ contrib,
    const int* __restrict__ ofs,
    const int* __restrict__ cnt,
    const float* __restrict__ bias,
    float* __restrict__ out) {
  int row = blockIdx.x * 4 + (threadIdx.x >> 6);
  int lane = threadIdx.x & 63;
  int rg = lane >> 3, ch = (lane & 7) * 8;
  int s = ofs[row], n = cnt[row];

  float acc[8];
#pragma unroll
  for (int i = 0; i < 8; i++) acc[i] = 0.f;

  int j = rg;
  for (; j + 8 < n; j += 16) {
    short8 v0 = __builtin_nontemporal_load((const short8*)&contrib[(size_t)(s + j) * 64 + ch]);
    short8 v1 = __builtin_nontemporal_load((const short8*)&contrib[(size_t)(s + j + 8) * 64 + ch]);
#pragma unroll
    for (int i = 0; i < 8; i++)
      acc[i] += __uint_as_float((unsigned int)(unsigned short)v0[i] << 16);
#pragma unroll
    for (int i = 0; i < 8; i++)
      acc[i] += __uint_as_float((unsigned int)(unsigned short)v1[i] << 16);
  }
  if (j < n) {
    short8 v0 = __builtin_nontemporal_load((const short8*)&contrib[(size_t)(s + j) * 64 + ch]);
#pragma unroll
    for (int i = 0; i < 8; i++)
      acc[i] += __uint_as_float((unsigned int)(unsigned short)v0[i] << 16);
  }

#pragma unroll
  for (int mask = 8; mask < 64; mask <<= 1)
#pragma unroll
    for (int i = 0; i < 8; i++) acc[i] += __shfl_xor(acc[i], mask, 64);

  if (rg == 0) {
    float4 b0 = *(const float4*)(bias + ch);
    float4 b1 = *(const float4*)(bias + ch + 4);
    float4 r0 = {acc[0] + b0.x, acc[1] + b0.y, acc[2] + b0.z, acc[3] + b0.w};
    float4 r1 = {acc[4] + b1.x, acc[5] + b1.y, acc[6] + b1.z, acc[7] + b1.w};
    *(float4*)(out + (size_t)row * 64 + ch) = r0;
    *(float4*)(out + (size_t)row * 64 + ch + 4) = r1;
  }
}

// ---------------- fallback (atomic path) ----------------

__global__ __launch_bounds__(256) void init_out_kernel(float* __restrict__ out,
                                                       const float* __restrict__ bias) {
  int i = blockIdx.x * blockDim.x + threadIdx.x;
  float4 b = *(const float4*)(bias + ((i * 4) & 63));
  ((float4*)out)[i] = b;
}

__global__ __launch_bounds__(256) void spconv_atomic_kernel(
    const unsigned short* __restrict__ inb,
    const unsigned short* __restrict__ wt,
    const int* __restrict__ imap, const int* __restrict__ omap,
    float* __restrict__ out) {
  __shared__ __align__(16) short A_lds[128 * 64];
  __shared__ __align__(16) short B_lds[64 * 64];

  int bid = blockIdx.x;
  int k = bid >> 9;
  int pbase = (bid & 511) * 128;
  int tid = threadIdx.x;
  int wave = tid >> 6, lane = tid & 63;
  int m = lane & 15, q = lane >> 4;

  const int* imk = imap + k * PPK;
  const int* omk = omap + k * PPK;
  const unsigned short* wtk = wt + k * 4096;

#pragma unroll
  for (int i = 0; i < 2; i++) {
    int id = wave * 2 + i;
    int t = id >> 1, s = id & 1;
    const unsigned short* g = wtk + (t * 16 + m) * 64 + s * 32 + q * 8;
    gl_lds16(g, &B_lds[(t * 128 + s * 64) * 8]);
  }
#pragma unroll
  for (int j = 0; j < 2; j++) {
    int r = wave * 2 + j;
    int row = imk[pbase + r * 16 + m];
    const unsigned short* g0 = inb + row * 64 + q * 8;
    gl_lds16(g0,      &A_lds[(r * 128)      * 8]);
    gl_lds16(g0 + 32, &A_lds[(r * 128 + 64) * 8]);
  }
  __syncthreads();

  const short8* Af = (const short8*)A_lds;
  const short8* Bf = (const short8*)B_lds;
  short8 a[2][2], b[4][2];
#pragma unroll
  for (int r2 = 0; r2 < 2; r2++) {
    int r = wave * 2 + r2;
#pragma unroll
    for (int s = 0; s < 2; s++) a[r2][s] = Af[r * 128 + s * 64 + lane];
  }
#pragma unroll
  for (int t = 0; t < 4; t++)
#pragma unroll
    for (int s = 0; s < 2; s++) b[t][s] = Bf[t * 128 + s * 64 + lane];

  f32x4 acc[2][4];
#pragma unroll
  for (int r2 = 0; r2 < 2; r2++)
#pragma unroll
    for (int t = 0; t < 4; t++) {
      f32x4 c = {0.f, 0.f, 0.f, 0.f};
      c = __builtin_amdgcn_mfma_f32_16x16x32_bf16(a[r2][0], b[t][0], c, 0, 0, 0);
      c = __builtin_amdgcn_mfma_f32_16x16x32_bf16(a[r2][1], b[t][1], c, 0, 0, 0);
      acc[r2][t] = c;
    }

  int orow[2][4];
#pragma unroll
  for (int r2 = 0; r2 < 2; r2++) {
    int pr = pbase + (wave * 2 + r2) * 16 + q * 4;
#pragma unroll
    for (int reg = 0; reg < 4; reg++) orow[r2][reg] = omk[pr + reg];
  }
#pragma unroll
  for (int r2 = 0; r2 < 2; r2++)
#pragma unroll
    for (int t = 0; t < 4; t++)
#pragma unroll
      for (int reg = 0; reg < 4; reg++)
        atomicAdd(out + (size_t)orow[r2][reg] * 64 + t * 16 + m, acc[r2][t][reg]);
}

// ---------------- launch ----------------

extern "C" void kernel_launch(void* const* d_in, const int* in_sizes, int n_in,
                              void* d_out, int out_size, void* d_ws, size_t ws_size,
                              hipStream_t stream) {
  const float* in_feats = (const float*)d_in[0];
  const float* kern     = (const float*)d_in[1];
  const float* bias     = (const float*)d_in[2];
  const int*   imap     = (const int*)d_in[3];
  const int*   omap     = (const int*)d_in[4];
  float* out = (float*)d_out;

  char* ws = (char*)d_ws;
  size_t off = 0;
  auto alloc = [&](size_t bytes) { size_t o = off; off = (off + bytes + 255) & ~(size_t)255; return o; };

  size_t o_inb   = alloc((size_t)N_VOX * CIN * 2);        // 16.78 MB
  size_t o_wt    = alloc((size_t)KVOL * CIN * COUT * 2);  // 0.22 MB
  size_t o_cts   = alloc((size_t)NB * SORT_BLOCKS * 4);   // 1.77 MB (ofs/cnt alias here)
  size_t o_bb    = alloc((size_t)NB * SORT_BLOCKS * 4);   // 1.77 MB
  size_t o_tot   = alloc((size_t)NB * 4);                 // 2 KB
  size_t o_islot = alloc((size_t)TOT * 4);                // 7.08 MB
  size_t o_ctb   = alloc((size_t)TOT * 64 * 2);           // 226.5 MB
  size_t needed = off;

  unsigned short* inb = (unsigned short*)(ws + o_inb);
  unsigned short* wt  = (unsigned short*)(ws + o_wt);
  int* counts    = (int*)(ws + o_cts);
  int* blockbase = (int*)(ws + o_bb);
  int* totals    = (int*)(ws + o_tot);
  int* islotf    = (int*)(ws + o_islot);
  unsigned short* ctb = (unsigned short*)(ws + o_ctb);
  // pairs (7.08 MB) aliases the ctb region: pairs lifetime [scatter, refine],
  // ctb lifetime [store, reduce] -- disjoint, stream-ordered.
  unsigned int* pairs = (unsigned int*)(ws + o_ctb);
  // ofs/cnt (1.05 MB) alias counts: counts dies after scan_blocks; refine writes
  // ofs/cnt strictly later -- disjoint, stream-ordered.
  int* ofs = (int*)(ws + o_cts);
  int* cnt = ofs + N_VOX;

  bool fast = (ws_size >= needed);

  if (fast) {
    prep_hist_kernel<<<SORT_BLOCKS + 4096 + KVOL, 256, 0, stream>>>(
        in_feats, inb, kern, wt, omap, counts, 1);
    scan_blocks_kernel<<<NB, 256, 0, stream>>>(counts, blockbase, totals);
    scatter_kernel<<<SORT_BLOCKS, 256, 0, stream>>>(omap, blockbase, totals, pairs);
    refine_kernel<<<NB, 256, 0, stream>>>(pairs, totals, islotf, ofs, cnt);
    spconv_store_kernel<<<GEMM_BLOCKS, 256, 0, stream>>>(inb, wt, imap, islotf, ctb);
    reduce_kernel<<<N_VOX / 4, 256, 0, stream>>>(ctb, ofs, cnt, bias, out);
  } else {
    prep_hist_kernel<<<4096 + KVOL, 256, 0, stream>>>(
        in_feats, inb, kern, wt, omap, nullptr, 0);
    init_out_kernel<<<(N_VOX * COUT / 4) / 256, 256, 0, stream>>>(out, bias);
    spconv_atomic_kernel<<<GEMM_BLOCKS, 256, 0, stream>>>(inb, wt, imap, omap, out);
  }
}

// Round 9
// 258.034 us; speedup vs baseline: 1.0849x; 1.0124x over previous
//
#include <hip/hip_runtime.h>
#include <hip/hip_bf16.h>
#include <stdint.h>

#define N_VOX 131072
#define KVOL  27
#define PPK   65536
#define CIN   64
#define COUT  64
#define TOT   (KVOL * PPK)         // 1769472 pairs
#define SORT_BLOCKS 864            // hist/scatter blocks, 2048 pairs each
#define GEMM_BLOCKS (KVOL * (PPK / 128))  // 13824
#define NB    512                  // buckets = key>>8 (256 keys each)

typedef __attribute__((ext_vector_type(8))) short short8;
typedef __attribute__((ext_vector_type(4))) float f32x4;

// inclusive Hillis-Steele scan over 512 ints in s[] using 256 threads
#define SCAN512(s, tid)                                       \
  for (int off = 1; off < 512; off <<= 1) {                   \
    int va_ = ((tid) >= off) ? s[(tid) - off] : 0;            \
    int vb_ = (((tid) + 256) >= off) ? s[(tid) + 256 - off] : 0; \
    __syncthreads();                                          \
    s[(tid)] += va_; s[(tid) + 256] += vb_;                   \
    __syncthreads();                                          \
  }

__device__ __forceinline__ void gl_lds16(const void* g, void* l) {
  __builtin_amdgcn_global_load_lds(
      (const __attribute__((address_space(1))) unsigned int*)g,
      (__attribute__((address_space(3))) unsigned int*)l,
      16, 0, 0);
}

__device__ __forceinline__ unsigned short f2bf(float f) {
  __hip_bfloat16 h = __float2bfloat16(f);
  return *reinterpret_cast<unsigned short*>(&h);
}

// ---------------- k1: fused cast + weight transpose + bucket histogram ----------------

__global__ __launch_bounds__(256) void prep_hist_kernel(
    const float* __restrict__ in, unsigned short* __restrict__ inb,
    const float* __restrict__ w, unsigned short* __restrict__ wt,
    const int* __restrict__ omap, int* __restrict__ counts, int do_sort) {
  int b = blockIdx.x;
  if (do_sort) {
    if (b < SORT_BLOCKS) {
      __shared__ unsigned int hist[NB];
      int tid = threadIdx.x;
      hist[tid] = 0; hist[tid + 256] = 0;
      __syncthreads();
      int e0 = (b * 256 + tid) * 8;
      int4 o0 = *(const int4*)(omap + e0);
      int4 o1 = *(const int4*)(omap + e0 + 4);
      atomicAdd(&hist[(unsigned)o0.x >> 8], 1u);
      atomicAdd(&hist[(unsigned)o0.y >> 8], 1u);
      atomicAdd(&hist[(unsigned)o0.z >> 8], 1u);
      atomicAdd(&hist[(unsigned)o0.w >> 8], 1u);
      atomicAdd(&hist[(unsigned)o1.x >> 8], 1u);
      atomicAdd(&hist[(unsigned)o1.y >> 8], 1u);
      atomicAdd(&hist[(unsigned)o1.z >> 8], 1u);
      atomicAdd(&hist[(unsigned)o1.w >> 8], 1u);
      __syncthreads();
      counts[(size_t)b * NB + tid]       = (int)hist[tid];
      counts[(size_t)b * NB + tid + 256] = (int)hist[tid + 256];
      return;
    }
    b -= SORT_BLOCKS;
  }
  if (b < 4096) {
    int i = b * 256 + threadIdx.x;
    const float4* in4 = (const float4*)in;
    float4 f0 = in4[2 * i], f1 = in4[2 * i + 1];
    union { unsigned short u[8]; short8 v; } r;
    r.u[0] = f2bf(f0.x); r.u[1] = f2bf(f0.y); r.u[2] = f2bf(f0.z); r.u[3] = f2bf(f0.w);
    r.u[4] = f2bf(f1.x); r.u[5] = f2bf(f1.y); r.u[6] = f2bf(f1.z); r.u[7] = f2bf(f1.w);
    ((short8*)inb)[i] = r.v;
  } else {
    int k = b - 4096;
    const float* wk = w + k * CIN * COUT;
    unsigned short* wtk = wt + k * CIN * COUT;
    for (int idx = threadIdx.x; idx < CIN * COUT; idx += 256) {
      int c = idx >> 6, o = idx & 63;
      wtk[o * 64 + c] = f2bf(wk[idx]);
    }
  }
}

// ---------------- k2: per-bucket exclusive scan over the 864 block counts ----------------

__global__ __launch_bounds__(256) void scan_blocks_kernel(
    const int* __restrict__ counts, int* __restrict__ blockbase,
    int* __restrict__ totals) {
  __shared__ int s[256];
  int b = blockIdx.x, t = threadIdx.x;
  int c0 = 0, c1 = 0, c2 = 0, c3 = 0;
  if (t < 216) {
    c0 = counts[(size_t)(4 * t + 0) * NB + b];
    c1 = counts[(size_t)(4 * t + 1) * NB + b];
    c2 = counts[(size_t)(4 * t + 2) * NB + b];
    c3 = counts[(size_t)(4 * t + 3) * NB + b];
  }
  int sum = c0 + c1 + c2 + c3;
  s[t] = sum; __syncthreads();
  for (int off = 1; off < 256; off <<= 1) {
    int v = (t >= off) ? s[t - off] : 0;
    __syncthreads();
    s[t] += v;
    __syncthreads();
  }
  int excl = s[t] - sum;
  int* brow = blockbase + (size_t)b * SORT_BLOCKS;
  if (t < 216) {
    brow[t * 4]     = excl;
    brow[t * 4 + 1] = excl + c0;
    brow[t * 4 + 2] = excl + c0 + c1;
    brow[t * 4 + 3] = excl + c0 + c1 + c2;
  }
  if (t == 255) totals[b] = s[255];
}

// ---------------- k3: scatter packed pairs into bucket regions ----------------

__global__ __launch_bounds__(256) void scatter_kernel(
    const int* __restrict__ omap, const int* __restrict__ blockbase,
    const int* __restrict__ totals, unsigned int* __restrict__ pairs) {
  __shared__ int ts[NB];
  __shared__ unsigned int gb[NB];
  __shared__ unsigned int cur[NB];
  int b = blockIdx.x, tid = threadIdx.x;
  int t0 = totals[tid], t1 = totals[tid + 256];
  ts[tid] = t0; ts[tid + 256] = t1;
  __syncthreads();
  SCAN512(ts, tid);
  gb[tid]       = (unsigned)(ts[tid] - t0 +
                    blockbase[(size_t)tid * SORT_BLOCKS + b]);
  gb[tid + 256] = (unsigned)(ts[tid + 256] - t1 +
                    blockbase[(size_t)(tid + 256) * SORT_BLOCKS + b]);
  cur[tid] = 0; cur[tid + 256] = 0;
  __syncthreads();
  int e0 = (b * 256 + tid) * 8;
  int4 o0 = *(const int4*)(omap + e0);
  int4 o1 = *(const int4*)(omap + e0 + 4);
  unsigned int key[8] = {(unsigned)o0.x, (unsigned)o0.y, (unsigned)o0.z, (unsigned)o0.w,
                         (unsigned)o1.x, (unsigned)o1.y, (unsigned)o1.z, (unsigned)o1.w};
#pragma unroll
  for (int i = 0; i < 8; i++) {
    unsigned int bk = key[i] >> 8;
    unsigned int r = atomicAdd(&cur[bk], 1u);
    unsigned int pos = gb[bk] + r;
    pairs[pos] = (((unsigned)(e0 + i)) << 8) | (key[i] & 255u);
  }
}

// ---------------- k4: refine buckets to full-key order ----------------

__global__ __launch_bounds__(256) void refine_kernel(
    const unsigned int* __restrict__ pairs, const int* __restrict__ totals,
    int* __restrict__ islotf, int* __restrict__ ofs, int* __restrict__ cnt) {
  __shared__ int ts[NB];
  __shared__ unsigned int hist[256];
  __shared__ unsigned int scn[256];
  __shared__ unsigned int cur[256];
  int b = blockIdx.x, t = threadIdx.x;
  int t0 = totals[t], t1 = totals[t + 256];
  ts[t] = t0; ts[t + 256] = t1;
  hist[t] = 0;
  __syncthreads();
  SCAN512(ts, t);
  __shared__ int sb_s, n_s;
  if (t == 0) { n_s = totals[b]; sb_s = ts[b] - n_s; }
  __syncthreads();
  int sb = sb_s, n = n_s;

  for (int i = t; i < n; i += 256)
    atomicAdd(&hist[pairs[sb + i] & 255u], 1u);
  __syncthreads();
  unsigned int h = hist[t];
  scn[t] = h;
  __syncthreads();
  for (int off = 1; off < 256; off <<= 1) {
    unsigned int v = (t >= off) ? scn[t - off] : 0;
    __syncthreads();
    scn[t] += v;
    __syncthreads();
  }
  unsigned int excl = scn[t] - h;
  ofs[b * 256 + t] = sb + (int)excl;
  cnt[b * 256 + t] = (int)h;
  cur[t] = excl;
  __syncthreads();
  for (int i = t; i < n; i += 256) {
    unsigned int v = pairs[sb + i];
    unsigned int r = atomicAdd(&cur[v & 255u], 1u);
    islotf[v >> 8] = sb + (int)r;
  }
}

// ---------------- k5: gather -> MFMA -> CACHED stores at fully-sorted positions ----------------
// contrib (226.5 MB) fits the 256 MB L3 and is read exactly once by the very
// next kernel -> write-allocate has guaranteed single reuse. nt stores pushed
// all 221 MB to HBM (r8: WRITE_SIZE=221MB in-dispatch); cached stores let L3
// absorb the burst and serve the reduce.

__global__ __launch_bounds__(256) void spconv_store_kernel(
    const unsigned short* __restrict__ inb,   // [N][64] bf16
    const unsigned short* __restrict__ wt,    // [27][COUT][CIN] bf16
    const int* __restrict__ imap,
    const int* __restrict__ islotf,           // e -> final slot (direct)
    unsigned short* __restrict__ contrib) {   // [TOT][64] bf16, key-sorted
  __shared__ __align__(16) char smem[24576];
  short* A_lds = (short*)smem;            // 16 KB: 128 pairs x 64 cin (fragment-major)
  short* B_lds = (short*)(smem + 16384);  //  8 KB: 64 cout x 64 cin
  short* C_sh  = (short*)smem;            // epilogue: [128][72] bf16
  __shared__ int perm_s[128];

  int bid = blockIdx.x;
  int k = bid >> 9;
  int pbase = (bid & 511) * 128;
  int tid = threadIdx.x;
  int wave = tid >> 6, lane = tid & 63;
  int m = lane & 15, q = lane >> 4;

  const int* imk = imap + k * PPK;
  const unsigned short* wtk = wt + k * 4096;

  if (tid < 128) perm_s[tid] = islotf[k * PPK + pbase + tid];

#pragma unroll
  for (int i = 0; i < 2; i++) {
    int id = wave * 2 + i;
    int t = id >> 1, s = id & 1;
    const unsigned short* g = wtk + (t * 16 + m) * 64 + s * 32 + q * 8;
    gl_lds16(g, &B_lds[(t * 128 + s * 64) * 8]);
  }
#pragma unroll
  for (int j = 0; j < 2; j++) {
    int r = wave * 2 + j;
    int row = imk[pbase + r * 16 + m];
    const unsigned short* g0 = inb + row * 64 + q * 8;
    gl_lds16(g0,      &A_lds[(r * 128)      * 8]);
    gl_lds16(g0 + 32, &A_lds[(r * 128 + 64) * 8]);
  }
  __syncthreads();

  const short8* Af = (const short8*)A_lds;
  const short8* Bf = (const short8*)B_lds;

  short8 a[2][2], b[4][2];
#pragma unroll
  for (int r2 = 0; r2 < 2; r2++) {
    int r = wave * 2 + r2;
#pragma unroll
    for (int s = 0; s < 2; s++) a[r2][s] = Af[r * 128 + s * 64 + lane];
  }
#pragma unroll
  for (int t = 0; t < 4; t++)
#pragma unroll
    for (int s = 0; s < 2; s++) b[t][s] = Bf[t * 128 + s * 64 + lane];

  __syncthreads();   // frag reads done before LDS reuse for C

  f32x4 acc[2][4];
#pragma unroll
  for (int r2 = 0; r2 < 2; r2++)
#pragma unroll
    for (int t = 0; t < 4; t++) {
      f32x4 c = {0.f, 0.f, 0.f, 0.f};
      c = __builtin_amdgcn_mfma_f32_16x16x32_bf16(a[r2][0], b[t][0], c, 0, 0, 0);
      c = __builtin_amdgcn_mfma_f32_16x16x32_bf16(a[r2][1], b[t][1], c, 0, 0, 0);
      acc[r2][t] = c;
    }

  // C layout: row(pair) = q*4 + reg, col(cout) = t*16 + m
#pragma unroll
  for (int r2 = 0; r2 < 2; r2++) {
    int pl = (wave * 2 + r2) * 16 + q * 4;
#pragma unroll
    for (int t = 0; t < 4; t++)
#pragma unroll
      for (int reg = 0; reg < 4; reg++)
        C_sh[(pl + reg) * 72 + t * 16 + m] = (short)f2bf(acc[r2][t][reg]);
  }
  __syncthreads();

  // cached full-line stores to fully-sorted slots (L3-resident for the reduce)
#pragma unroll
  for (int i = 0; i < 4; i++) {
    int id = i * 256 + tid;
    int row = id >> 3, ch = (id & 7) * 8;
    short8 v = *(const short8*)&C_sh[row * 72 + ch];
    *((short8*)&contrib[(size_t)perm_s[row] * 64 + ch]) = v;
  }
}

// ---------------- k6: contiguous segmented reduce + bias (nt loads) ----------------
// nt loads still probe L2/L3 (r4: 50% L3 service even against nt stores) but
// don't allocate -- exactly right for the single-read consume of contrib.

__global__ __launch_bounds__(256) void reduce_kernel(
    const unsigned short* __restrict__ contrib,
    const int* __restrict__ ofs,
    const int* __restrict__ cnt,
    const float* __restrict__ bias,
    float* __restrict__ out) {
  int row = blockIdx.x * 4 + (threadIdx.x >> 6);
  int lane = threadIdx.x & 63;
  int rg = lane >> 3, ch = (lane & 7) * 8;
  int s = ofs[row], n = cnt[row];

  float acc[8];
#pragma unroll
  for (int i = 0; i < 8; i++) acc[i] = 0.f;

  int j = rg;
  for (; j + 8 < n; j += 16) {
    short8 v0 = __builtin_nontemporal_load((const short8*)&contrib[(size_t)(s + j) * 64 + ch]);
    short8 v1 = __builtin_nontemporal_load((const short8*)&contrib[(size_t)(s + j + 8) * 64 + ch]);
#pragma unroll
    for (int i = 0; i < 8; i++)
      acc[i] += __uint_as_float((unsigned int)(unsigned short)v0[i] << 16);
#pragma unroll
    for (int i = 0; i < 8; i++)
      acc[i] += __uint_as_float((unsigned int)(unsigned short)v1[i] << 16);
  }
  if (j < n) {
    short8 v0 = __builtin_nontemporal_load((const short8*)&contrib[(size_t)(s + j) * 64 + ch]);
#pragma unroll
    for (int i = 0; i < 8; i++)
      acc[i] += __uint_as_float((unsigned int)(unsigned short)v0[i] << 16);
  }

#pragma unroll
  for (int mask = 8; mask < 64; mask <<= 1)
#pragma unroll
    for (int i = 0; i < 8; i++) acc[i] += __shfl_xor(acc[i], mask, 64);

  if (rg == 0) {
    float4 b0 = *(const float4*)(bias + ch);
    float4 b1 = *(const float4*)(bias + ch + 4);
    float4 r0 = {acc[0] + b0.x, acc[1] + b0.y, acc[2] + b0.z, acc[3] + b0.w};
    float4 r1 = {acc[4] + b1.x, acc[5] + b1.y, acc[6] + b1.z, acc[7] + b1.w};
    *(float4*)(out + (size_t)row * 64 + ch) = r0;
    *(float4*)(out + (size_t)row * 64 + ch + 4) = r1;
  }
}

// ---------------- fallback (atomic path) ----------------

__global__ __launch_bounds__(256) void init_out_kernel(float* __restrict__ out,
                                                       const float* __restrict__ bias) {
  int i = blockIdx.x * blockDim.x + threadIdx.x;
  float4 b = *(const float4*)(bias + ((i * 4) & 63));
  ((float4*)out)[i] = b;
}

__global__ __launch_bounds__(256) void spconv_atomic_kernel(
    const unsigned short* __restrict__ inb,
    const unsigned short* __restrict__ wt,
    const int* __restrict__ imap, const int* __restrict__ omap,
    float* __restrict__ out) {
  __shared__ __align__(16) short A_lds[128 * 64];
  __shared__ __align__(16) short B_lds[64 * 64];

  int bid = blockIdx.x;
  int k = bid >> 9;
  int pbase = (bid & 511) * 128;
  int tid = threadIdx.x;
  int wave = tid >> 6, lane = tid & 63;
  int m = lane & 15, q = lane >> 4;

  const int* imk = imap + k * PPK;
  const int* omk = omap + k * PPK;
  const unsigned short* wtk = wt + k * 4096;

#pragma unroll
  for (int i = 0; i < 2; i++) {
    int id = wave * 2 + i;
    int t = id >> 1, s = id & 1;
    const unsigned short* g = wtk + (t * 16 + m) * 64 + s * 32 + q * 8;
    gl_lds16(g, &B_lds[(t * 128 + s * 64) * 8]);
  }
#pragma unroll
  for (int j = 0; j < 2; j++) {
    int r = wave * 2 + j;
    int row = imk[pbase + r * 16 + m];
    const unsigned short* g0 = inb + row * 64 + q * 8;
    gl_lds16(g0,      &A_lds[(r * 128)      * 8]);
    gl_lds16(g0 + 32, &A_lds[(r * 128 + 64) * 8]);
  }
  __syncthreads();

  const short8* Af = (const short8*)A_lds;
  const short8* Bf = (const short8*)B_lds;
  short8 a[2][2], b[4][2];
#pragma unroll
  for (int r2 = 0; r2 < 2; r2++) {
    int r = wave * 2 + r2;
#pragma unroll
    for (int s = 0; s < 2; s++) a[r2][s] = Af[r * 128 + s * 64 + lane];
  }
#pragma unroll
  for (int t = 0; t < 4; t++)
#pragma unroll
    for (int s = 0; s < 2; s++) b[t][s] = Bf[t * 128 + s * 64 + lane];

  f32x4 acc[2][4];
#pragma unroll
  for (int r2 = 0; r2 < 2; r2++)
#pragma unroll
    for (int t = 0; t < 4; t++) {
      f32x4 c = {0.f, 0.f, 0.f, 0.f};
      c = __builtin_amdgcn_mfma_f32_16x16x32_bf16(a[r2][0], b[t][0], c, 0, 0, 0);
      c = __builtin_amdgcn_mfma_f32_16x16x32_bf16(a[r2][1], b[t][1], c, 0, 0, 0);
      acc[r2][t] = c;
    }

  int orow[2][4];
#pragma unroll
  for (int r2 = 0; r2 < 2; r2++) {
    int pr = pbase + (wave * 2 + r2) * 16 + q * 4;
#pragma unroll
    for (int reg = 0; reg < 4; reg++) orow[r2][reg] = omk[pr + reg];
  }
#pragma unroll
  for (int r2 = 0; r2 < 2; r2++)
#pragma unroll
    for (int t = 0; t < 4; t++)
#pragma unroll
      for (int reg = 0; reg < 4; reg++)
        atomicAdd(out + (size_t)orow[r2][reg] * 64 + t * 16 + m, acc[r2][t][reg]);
}

// ---------------- launch ----------------

extern "C" void kernel_launch(void* const* d_in, const int* in_sizes, int n_in,
                              void* d_out, int out_size, void* d_ws, size_t ws_size,
                              hipStream_t stream) {
  const float* in_feats = (const float*)d_in[0];
  const float* kern     = (const float*)d_in[1];
  const float* bias     = (const float*)d_in[2];
  const int*   imap     = (const int*)d_in[3];
  const int*   omap     = (const int*)d_in[4];
  float* out = (float*)d_out;

  char* ws = (char*)d_ws;
  size_t off = 0;
  auto alloc = [&](size_t bytes) { size_t o = off; off = (off + bytes + 255) & ~(size_t)255; return o; };

  size_t o_inb   = alloc((size_t)N_VOX * CIN * 2);        // 16.78 MB
  size_t o_wt    = alloc((size_t)KVOL * CIN * COUT * 2);  // 0.22 MB
  size_t o_cts   = alloc((size_t)NB * SORT_BLOCKS * 4);   // 1.77 MB (ofs/cnt alias here)
  size_t o_bb    = alloc((size_t)NB * SORT_BLOCKS * 4);   // 1.77 MB
  size_t o_tot   = alloc((size_t)NB * 4);                 // 2 KB
  size_t o_islot = alloc((size_t)TOT * 4);                // 7.08 MB
  size_t o_ctb   = alloc((size_t)TOT * 64 * 2);           // 226.5 MB
  size_t needed = off;

  unsigned short* inb = (unsigned short*)(ws + o_inb);
  unsigned short* wt  = (unsigned short*)(ws + o_wt);
  int* counts    = (int*)(ws + o_cts);
  int* blockbase = (int*)(ws + o_bb);
  int* totals    = (int*)(ws + o_tot);
  int* islotf    = (int*)(ws + o_islot);
  unsigned short* ctb = (unsigned short*)(ws + o_ctb);
  // pairs (7.08 MB) aliases the ctb region: pairs lifetime [scatter, refine],
  // ctb lifetime [store, reduce] -- disjoint, stream-ordered.
  unsigned int* pairs = (unsigned int*)(ws + o_ctb);
  // ofs/cnt (1.05 MB) alias counts: counts dies after scan_blocks; refine writes
  // ofs/cnt strictly later -- disjoint, stream-ordered.
  int* ofs = (int*)(ws + o_cts);
  int* cnt = ofs + N_VOX;

  bool fast = (ws_size >= needed);

  if (fast) {
    prep_hist_kernel<<<SORT_BLOCKS + 4096 + KVOL, 256, 0, stream>>>(
        in_feats, inb, kern, wt, omap, counts, 1);
    scan_blocks_kernel<<<NB, 256, 0, stream>>>(counts, blockbase, totals);
    scatter_kernel<<<SORT_BLOCKS, 256, 0, stream>>>(omap, blockbase, totals, pairs);
    refine_kernel<<<NB, 256, 0, stream>>>(pairs, totals, islotf, ofs, cnt);
    spconv_store_kernel<<<GEMM_BLOCKS, 256, 0, stream>>>(inb, wt, imap, islotf, ctb);
    reduce_kernel<<<N_VOX / 4, 256, 0, stream>>>(ctb, ofs, cnt, bias, out);
  } else {
    prep_hist_kernel<<<4096 + KVOL, 256, 0, stream>>>(
        in_feats, inb, kern, wt, omap, nullptr, 0);
    init_out_kernel<<<(N_VOX * COUT / 4) / 256, 256, 0, stream>>>(out, bias);
    spconv_atomic_kernel<<<GEMM_BLOCKS, 256, 0, stream>>>(inb, wt, imap, omap, out);
  }
}